// Round 5
// baseline (338.823 us; speedup 1.0000x reference)
//
#include <hip/hip_runtime.h>
#include <hip/hip_bf16.h>

#define BB 2
#define NN 2048
#define DD 128
#define BN (BB*NN)
#define CAP 128
#define TD 16
#define QSTR 256
#define SSTR 128
#define INV_SQRT_D 0.08838834764831845f

typedef __attribute__((ext_vector_type(8))) short short8;
typedef __attribute__((ext_vector_type(4))) float f32x4;

__device__ inline float b2f(unsigned short u) {
    union { unsigned int i; float f; } c; c.i = (unsigned int)u << 16; return c.f;
}
__device__ inline float b2f_hi(unsigned int raw) {
    union { unsigned int i; float f; } c; c.i = raw & 0xffff0000u; return c.f;
}
__device__ inline float b2f_lo(unsigned int raw) {
    union { unsigned int i; float f; } c; c.i = raw << 16; return c.f;
}

// ---------------------------------------------------------------------------
// Merged prep kernel (block-range dispatch):
//   bid < BN                : CSR scatter, one src row, fully coalesced reads.
//                             deg must be pre-zeroed (hipMemsetAsync).
//   BN <= bid < BN+1408     : weight transposes Wt1 (512) / Wt2 (896)
//   BN+1408 <= bid          : layer-0 rank-1 projection (256 row-tiles)
// ---------------------------------------------------------------------------
__global__ __launch_bounds__(256) void prep(
    const float* __restrict__ A, const float* __restrict__ edge,
    const float* __restrict__ node,
    const float* __restrict__ Wq0, const float* __restrict__ Wk0,
    const float* __restrict__ Wv0, const float* __restrict__ Ws0,
    const float* __restrict__ Wq1, const float* __restrict__ Wk1,
    const float* __restrict__ Wv1, const float* __restrict__ Ws1,
    const float* __restrict__ Wq2, const float* __restrict__ Wk2,
    const float* __restrict__ Wv2, const float* __restrict__ Ws2,
    __hip_bfloat16* __restrict__ Wt1, __hip_bfloat16* __restrict__ Wt2,
    float* __restrict__ q, __hip_bfloat16* __restrict__ kA,
    __hip_bfloat16* __restrict__ vA, float* __restrict__ s,
    int* __restrict__ deg, unsigned short* __restrict__ cols,
    float* __restrict__ evals)
{
    __shared__ float xnode[16];
    int bid = blockIdx.x;
    int tid = threadIdx.x;

    if (bid < BN) {
        // ---- CSR scatter: src row = bid, coalesced read of 2048 cols ----
        int b   = bid >> 11;              // bid / NN
        const size_t base = (size_t)bid * NN;
        int d0  = tid * 8;
        float4 a4 = *(const float4*)&A[base + d0];
        float4 a5 = *(const float4*)&A[base + d0 + 4];
        float4 e4 = *(const float4*)&edge[base + d0];
        float4 e5 = *(const float4*)&edge[base + d0 + 4];
        float av[8] = {a4.x, a4.y, a4.z, a4.w, a5.x, a5.y, a5.z, a5.w};
        float ew[8] = {e4.x, e4.y, e4.z, e4.w, e5.x, e5.y, e5.z, e5.w};
#pragma unroll
        for (int u = 0; u < 8; u++) {
            if (av[u] != 0.f) {
                int gdst = b * NN + d0 + u;
                int slot = atomicAdd(&deg[gdst], 1);
                if (slot < CAP) {
                    cols [(size_t)gdst * CAP + slot] = (unsigned short)bid;
                    evals[(size_t)gdst * CAP + slot] = ew[u] * av[u];
                }
            }
        }
    } else if (bid < BN + 1408) {
        int c = bid - BN;
        if (tid < DD) {
            const float *Wq, *Wk, *Wv, *Ws; __hip_bfloat16* Wt; int n, HD;
            if (c < 512) { Wq = Wq1; Wk = Wk1; Wv = Wv1; Ws = Ws1; Wt = Wt1; n = c;       HD = DD;     }
            else         { Wq = Wq2; Wk = Wk2; Wv = Wv2; Ws = Ws2; Wt = Wt2; n = c - 512; HD = 2 * DD; }
            const float* src; int ld; int col;
            if      (n < HD)     { src = Wq; col = n;          ld = HD; }
            else if (n < 2*HD)   { src = Wk; col = n - HD;     ld = HD; }
            else if (n < 3*HD)   { src = Wv; col = n - 2*HD;   ld = HD; }
            else                 { src = Ws; col = n - 3*HD;   ld = DD; }
            Wt[(size_t)n * DD + tid] = __float2bfloat16(src[(size_t)tid * ld + col]);
        }
    } else {
        // ---- layer-0 projection: 16 rows x 512 cols per block ----
        int row0 = (bid - (BN + 1408)) * 16;
        if (tid < 16) xnode[tid] = node[row0 + tid];
        __syncthreads();
        for (int i = tid; i < TD * 512; i += 256) {
            int r = i >> 9, col = i & 511;
            float xv = xnode[r];
            if (col < DD) {
                q[(size_t)(row0 + r) * QSTR + col] = xv * Wq0[col];
            } else if (col < 2*DD) {
                int lc = col - DD;
                kA[(size_t)(row0 + r) * 256 + lc] = __float2bfloat16(xv * Wk0[lc]);
            } else if (col < 3*DD) {
                int lc = col - 2*DD;
                vA[(size_t)(row0 + r) * 256 + lc] = __float2bfloat16(xv * Wv0[lc]);
            } else {
                int lc = col - 3*DD;
                s[(size_t)(row0 + r) * SSTR + lc] = xv * Ws0[lc];
            }
        }
    }
}

// ---------------------------------------------------------------------------
// Fused sparse attention + next-layer projection.
// k/v bf16 (L2-resident gather set). Inner loop unrolled x2 (8 edges/iter):
// all gathers for both 4-edge groups issue before either compute phase ->
// ~2x memory-level parallelism, halves dependent-latency count per row.
//   NCOLS == 0 -> final layer, write fp32 to out.
// ---------------------------------------------------------------------------
template<int H, bool MEANH, bool LNRELU, int NCOLS, int HDN, int KVSI, int KVSO>
__global__ __launch_bounds__(1024) void fused_attn(
    float* qio,                                   // in/out, stride QSTR
    const __hip_bfloat16* __restrict__ k,         // stride KVSI
    const __hip_bfloat16* __restrict__ v,         // stride KVSI
    float* sio,                                   // in/out, stride SSTR
    const int* __restrict__ deg,
    const unsigned short* __restrict__ cols,
    const float* __restrict__ evals, const float* __restrict__ We,
    const __hip_bfloat16* __restrict__ Wt,
    __hip_bfloat16* __restrict__ kn, __hip_bfloat16* __restrict__ vn, // stride KVSO
    float* __restrict__ out)
{
    const int HD = H * DD;
    int wid  = threadIdx.x >> 6;       // 0..15
    int lane = threadIdx.x & 63;
    int row0 = blockIdx.x * 16;
    int row  = row0 + wid;
    int sub  = lane >> 4;
    int s    = lane & 15;
    int c0   = lane * 2;

    __shared__ int            jc_s[16][CAP];
    __shared__ float          ev_s[16][CAP];
    __shared__ __hip_bfloat16 xs[16][136];   // +8 bf16 pad (16B-aligned rows)
    int*   jc = jc_s[wid];
    float* ev = ev_s[wid];

    int dg = min(deg[row], CAP);
    for (int m = lane; m < dg; m += 64) {
        jc[m] = (int)cols[(size_t)row * CAP + m];
        ev[m] = evals[(size_t)row * CAP + m];
    }
    // wave-private LDS: no barrier needed (compiler inserts lgkmcnt waits)

    float qh[H][8];
    float qeI[H];
#pragma unroll
    for (int h = 0; h < H; h++) {
        const float* qp = &qio[(size_t)row * QSTR + h * DD + s * 8];
        const float* wp = &We[h * DD + s * 8];
        float pe = 0.f;
#pragma unroll
        for (int t = 0; t < 8; t++) { qh[h][t] = qp[t]; pe += qp[t] * wp[t]; }
#pragma unroll
        for (int off = 1; off < 16; off <<= 1) pe += __shfl_xor(pe, off);
        qeI[h] = pe * INV_SQRT_D;
    }

    float l_acc[H], ew_acc[H], acc[H][2];
#pragma unroll
    for (int h = 0; h < H; h++) { l_acc[h] = 0.f; ew_acc[h] = 0.f; acc[h][0] = 0.f; acc[h][1] = 0.f; }

    for (int m0 = 0; m0 < dg; m0 += 8) {
        int   e0  = m0 + sub,       e1  = m0 + 4 + sub;
        bool  ok0 = e0 < dg,        ok1 = e1 < dg;
        int   ec0 = ok0 ? e0 : m0,  ec1 = ok1 ? e1 : m0;
        int   j0  = jc[ec0],        j1  = jc[ec1];
        float ee0 = ev[ec0],        ee1 = ev[ec1];

        int jb[8];
#pragma unroll
        for (int es = 0; es < 8; es++) jb[es] = jc[(m0 + es < dg) ? m0 + es : m0];

        // issue ALL gathers for both groups up front (memory-level parallelism)
        unsigned int vraw[H][8];
#pragma unroll
        for (int h = 0; h < H; h++)
#pragma unroll
            for (int es = 0; es < 8; es++)
                vraw[h][es] = *(const unsigned int*)&v[(size_t)jb[es] * KVSI + h * DD + c0];
        short8 kk0[H], kk1[H];
#pragma unroll
        for (int h = 0; h < H; h++) {
            kk0[h] = *(const short8*)&k[(size_t)j0 * KVSI + h * DD + s * 8];
            kk1[h] = *(const short8*)&k[(size_t)j1 * KVSI + h * DD + s * 8];
        }

#pragma unroll
        for (int h = 0; h < H; h++) {
            float p0 = qh[h][0]*b2f((unsigned short)kk0[h][0]) + qh[h][1]*b2f((unsigned short)kk0[h][1])
                     + qh[h][2]*b2f((unsigned short)kk0[h][2]) + qh[h][3]*b2f((unsigned short)kk0[h][3])
                     + qh[h][4]*b2f((unsigned short)kk0[h][4]) + qh[h][5]*b2f((unsigned short)kk0[h][5])
                     + qh[h][6]*b2f((unsigned short)kk0[h][6]) + qh[h][7]*b2f((unsigned short)kk0[h][7]);
            float p1 = qh[h][0]*b2f((unsigned short)kk1[h][0]) + qh[h][1]*b2f((unsigned short)kk1[h][1])
                     + qh[h][2]*b2f((unsigned short)kk1[h][2]) + qh[h][3]*b2f((unsigned short)kk1[h][3])
                     + qh[h][4]*b2f((unsigned short)kk1[h][4]) + qh[h][5]*b2f((unsigned short)kk1[h][5])
                     + qh[h][6]*b2f((unsigned short)kk1[h][6]) + qh[h][7]*b2f((unsigned short)kk1[h][7]);
#pragma unroll
            for (int off = 1; off < 16; off <<= 1) {
                p0 += __shfl_xor(p0, off);
                p1 += __shfl_xor(p1, off);
            }
            float sc0 = ok0 ? (p0 * INV_SQRT_D + qeI[h] * ee0) : -1e30f;
            float sc1 = ok1 ? (p1 * INV_SQRT_D + qeI[h] * ee1) : -1e30f;
            float a0 = __expf(fminf(sc0, 60.f));
            float a1 = __expf(fminf(sc1, 60.f));
            l_acc[h]  += a0 + a1;
            ew_acc[h] += a0 * ee0 + a1 * ee1;
            float al0[4], al1[4];
#pragma unroll
            for (int es = 0; es < 4; es++) { al0[es] = __shfl(a0, es * 16); al1[es] = __shfl(a1, es * 16); }
#pragma unroll
            for (int es = 0; es < 4; es++) {
                acc[h][0] += al0[es] * b2f_lo(vraw[h][es]) + al1[es] * b2f_lo(vraw[h][es + 4]);
                acc[h][1] += al0[es] * b2f_hi(vraw[h][es]) + al1[es] * b2f_hi(vraw[h][es + 4]);
            }
        }
    }

    // reduce l/ew across the 4 subgroups (values replicated within subgroup)
    float rh[H][2];
#pragma unroll
    for (int h = 0; h < H; h++) {
        float l  = l_acc[h]  + __shfl_xor(l_acc[h], 16);
        float ew = ew_acc[h] + __shfl_xor(ew_acc[h], 16);
        l  += __shfl_xor(l, 32);
        ew += __shfl_xor(ew, 32);
        float invZ = (l > 0.f) ? 1.f / l : 0.f;
        rh[h][0] = (acc[h][0] + ew * We[h * DD + c0])     * invZ;
        rh[h][1] = (acc[h][1] + ew * We[h * DD + c0 + 1]) * invZ;
    }
    float r0, r1;
    if constexpr (MEANH) {
        r0 = 0.5f * (rh[0][0] + rh[H - 1][0]);
        r1 = 0.5f * (rh[0][1] + rh[H - 1][1]);
    } else {
        r0 = rh[0][0]; r1 = rh[0][1];
    }
    float2 sk = *(const float2*)&sio[(size_t)row * SSTR + c0];
    r0 += sk.x; r1 += sk.y;

    if constexpr (LNRELU) {
        float sum = r0 + r1, sq = r0 * r0 + r1 * r1;
#pragma unroll
        for (int off = 32; off; off >>= 1) { sum += __shfl_xor(sum, off); sq += __shfl_xor(sq, off); }
        float mu  = sum * (1.f / DD);
        float var = sq * (1.f / DD) - mu * mu;
        float rs  = rsqrtf(var + 1e-5f);
        r0 = fmaxf((r0 - mu) * rs, 0.f);
        r1 = fmaxf((r1 - mu) * rs, 0.f);
    }

    if constexpr (NCOLS == 0) {
        float2 res; res.x = r0; res.y = r1;
        *(float2*)&out[(size_t)row * DD + c0] = res;
    } else {
        // stage bf16 x-tile in LDS, then MFMA-project into next-layer buffers
        __hip_bfloat162 o;
        o.x = __float2bfloat16(r0);
        o.y = __float2bfloat16(r1);
        *(__hip_bfloat162*)&xs[wid][c0] = o;
        __syncthreads();   // all attn reads (q/skip/k/v) drained before writes

        int m16 = lane & 15, quad = lane >> 4;
        short8 a[4];
#pragma unroll
        for (int ks = 0; ks < 4; ks++)
            a[ks] = *(const short8*)&xs[m16][ks * 32 + quad * 8];

#pragma unroll 1
        for (int tile = wid; tile < NCOLS / 16; tile += 16) {
            int n0 = tile * 16;
            f32x4 pacc = {0.f, 0.f, 0.f, 0.f};
#pragma unroll
            for (int ks = 0; ks < 4; ks++) {
                const short8* bp = (const short8*)&Wt[(size_t)(n0 + m16) * DD + ks * 32 + quad * 8];
                pacc = __builtin_amdgcn_mfma_f32_16x16x32_bf16(a[ks], *bp, pacc, 0, 0, 0);
            }
            if (n0 < HDN) {                                   // q: fp32 in place
#pragma unroll
                for (int r = 0; r < 4; r++)
                    qio[(size_t)(row0 + quad * 4 + r) * QSTR + n0 + m16] = pacc[r];
            } else if (n0 < 2*HDN) {                          // k: bf16
                int lc = n0 - HDN;
#pragma unroll
                for (int r = 0; r < 4; r++)
                    kn[(size_t)(row0 + quad * 4 + r) * KVSO + lc + m16] = __float2bfloat16(pacc[r]);
            } else if (n0 < 3*HDN) {                          // v: bf16
                int lc = n0 - 2*HDN;
#pragma unroll
                for (int r = 0; r < 4; r++)
                    vn[(size_t)(row0 + quad * 4 + r) * KVSO + lc + m16] = __float2bfloat16(pacc[r]);
            } else {                                          // skip: fp32 in place
                int lc = n0 - 3*HDN;
#pragma unroll
                for (int r = 0; r < 4; r++)
                    sio[(size_t)(row0 + quad * 4 + r) * SSTR + lc + m16] = pacc[r];
            }
        }
    }
}

// ---------------------------------------------------------------------------
extern "C" void kernel_launch(void* const* d_in, const int* in_sizes, int n_in,
                              void* d_out, int out_size, void* d_ws, size_t ws_size,
                              hipStream_t stream)
{
    const float* node = (const float*)d_in[0];
    const float* edge = (const float*)d_in[1];
    const float* A    = (const float*)d_in[2];
    const float* Wq[3] = {(const float*)d_in[3],  (const float*)d_in[8],  (const float*)d_in[13]};
    const float* Wk[3] = {(const float*)d_in[4],  (const float*)d_in[9],  (const float*)d_in[14]};
    const float* Wv[3] = {(const float*)d_in[5],  (const float*)d_in[10], (const float*)d_in[15]};
    const float* We[3] = {(const float*)d_in[6],  (const float*)d_in[11], (const float*)d_in[16]};
    const float* Ws[3] = {(const float*)d_in[7],  (const float*)d_in[12], (const float*)d_in[17]};

    // workspace carve (~15.4 MiB)
    char* p = (char*)d_ws;
    float*          q  = (float*)p;          p += (size_t)BN * QSTR * 4;
    float*          s  = (float*)p;          p += (size_t)BN * SSTR * 4;
    __hip_bfloat16* kA = (__hip_bfloat16*)p; p += (size_t)BN * 256 * 2;
    __hip_bfloat16* vA = (__hip_bfloat16*)p; p += (size_t)BN * 256 * 2;
    __hip_bfloat16* kB = (__hip_bfloat16*)p; p += (size_t)BN * 128 * 2;
    __hip_bfloat16* vB = (__hip_bfloat16*)p; p += (size_t)BN * 128 * 2;
    __hip_bfloat16* Wt1 = (__hip_bfloat16*)p; p += (size_t)512 * DD * 2;
    __hip_bfloat16* Wt2 = (__hip_bfloat16*)p; p += (size_t)896 * DD * 2;
    int*            degb = (int*)p;            p += (size_t)BN * 4;
    float*          evb  = (float*)p;          p += (size_t)BN * CAP * 4;
    unsigned short* colb = (unsigned short*)p; p += (size_t)BN * CAP * 2;

    hipMemsetAsync(degb, 0, (size_t)BN * 4, stream);
    prep<<<BN + 1408 + BN / 16, 256, 0, stream>>>(
        A, edge, node,
        Wq[0], Wk[0], Wv[0], Ws[0],
        Wq[1], Wk[1], Wv[1], Ws[1],
        Wq[2], Wk[2], Wv[2], Ws[2],
        Wt1, Wt2, q, kA, vA, s, degb, colb, evb);

    // app sequence l = {0,1,2,1,2,1,2}; each kernel = attn(l) + proj(next l)
    fused_attn<1, false, true, 512, 128, 256, 128><<<BN / 16, 1024, 0, stream>>>(   // l0 -> proj l1
        q, kA, vA, s, degb, colb, evb, We[0], Wt1, kB, vB, nullptr);
    fused_attn<1, false, true, 896, 256, 128, 256><<<BN / 16, 1024, 0, stream>>>(   // l1 -> proj l2
        q, kB, vB, s, degb, colb, evb, We[1], Wt2, kA, vA, nullptr);
    fused_attn<2, true, false, 512, 128, 256, 128><<<BN / 16, 1024, 0, stream>>>(   // l2 -> proj l1
        q, kA, vA, s, degb, colb, evb, We[2], Wt1, kB, vB, nullptr);
    fused_attn<1, false, true, 896, 256, 128, 256><<<BN / 16, 1024, 0, stream>>>(   // l1 -> proj l2
        q, kB, vB, s, degb, colb, evb, We[1], Wt2, kA, vA, nullptr);
    fused_attn<2, true, false, 512, 128, 256, 128><<<BN / 16, 1024, 0, stream>>>(   // l2 -> proj l1
        q, kA, vA, s, degb, colb, evb, We[2], Wt1, kB, vB, nullptr);
    fused_attn<1, false, true, 896, 256, 128, 256><<<BN / 16, 1024, 0, stream>>>(   // l1 -> proj l2
        q, kB, vB, s, degb, colb, evb, We[1], Wt2, kA, vA, nullptr);
    fused_attn<2, true, false, 0, 0, 256, 0><<<BN / 16, 1024, 0, stream>>>(         // l2 -> output
        q, kA, vA, s, degb, colb, evb, We[2], nullptr, nullptr, nullptr, (float*)d_out);
}

// Round 6
// 320.885 us; speedup vs baseline: 1.0559x; 1.0559x over previous
//
#include <hip/hip_runtime.h>
#include <hip/hip_bf16.h>

#define BB 2
#define NN 2048
#define DD 128
#define BN (BB*NN)
#define CAP 128
#define TD 16
#define QSTR 256
#define SSTR 128
#define INV_SQRT_D 0.08838834764831845f

typedef __attribute__((ext_vector_type(8))) short short8;
typedef __attribute__((ext_vector_type(4))) float f32x4;

__device__ inline float b2f(unsigned short u) {
    union { unsigned int i; float f; } c; c.i = (unsigned int)u << 16; return c.f;
}
__device__ inline float b2f_hi(unsigned int raw) {
    union { unsigned int i; float f; } c; c.i = raw & 0xffff0000u; return c.f;
}
__device__ inline float b2f_lo(unsigned int raw) {
    union { unsigned int i; float f; } c; c.i = raw << 16; return c.f;
}

// ---------------------------------------------------------------------------
// Merged prep kernel, block-range dispatch (one launch, no memset):
//   bid < 256          : LDS-tiled CSR build (REVERTED to the verified
//                        16-dst-stripe algorithm: LDS atomics, no global
//                        atomics — round-5's global-scatter was a measured
//                        regression: 51.5 us @ 1.16 TB/s, latency-bound).
//   256 <= bid < 1664  : weight transposes Wt1 (512) / Wt2 (896)
//   1664 <= bid < 1920 : layer-0 rank-1 projection (256 row-tiles)
// ---------------------------------------------------------------------------
__global__ __launch_bounds__(256) void prep(
    const float* __restrict__ A, const float* __restrict__ edge,
    const float* __restrict__ node,
    const float* __restrict__ Wq0, const float* __restrict__ Wk0,
    const float* __restrict__ Wv0, const float* __restrict__ Ws0,
    const float* __restrict__ Wq1, const float* __restrict__ Wk1,
    const float* __restrict__ Wv1, const float* __restrict__ Ws1,
    const float* __restrict__ Wq2, const float* __restrict__ Wk2,
    const float* __restrict__ Wv2, const float* __restrict__ Ws2,
    __hip_bfloat16* __restrict__ Wt1, __hip_bfloat16* __restrict__ Wt2,
    float* __restrict__ q, __hip_bfloat16* __restrict__ kA,
    __hip_bfloat16* __restrict__ vA, float* __restrict__ s,
    int* __restrict__ deg, unsigned short* __restrict__ cols,
    float* __restrict__ evals)
{
    __shared__ int   cnt[TD];
    __shared__ int   csh[TD][CAP];
    __shared__ float esh[TD][CAP];
    __shared__ float xnode[16];

    int bid = blockIdx.x;
    int tid = threadIdx.x;

    if (bid < 256) {
        // ---- LDS-tiled CSR build: 16 dst rows per block ----
        int b    = bid >> 7;              // bid / 128
        int dst0 = (bid & 127) * TD;

        if (tid < TD) cnt[tid] = 0;
        __syncthreads();

        int srcOff = tid >> 2;
        int dOff   = (tid & 3) * 4;
        const size_t base = (size_t)b * NN * NN + dst0 + dOff;

#pragma unroll 2
        for (int s0 = 0; s0 < NN; s0 += 64) {
            int src = s0 + srcOff;
            float4 a4 = *(const float4*)&A[base + (size_t)src * NN];
            float4 e4 = *(const float4*)&edge[base + (size_t)src * NN];
            int gsrc = b * NN + src;
            float av[4] = {a4.x, a4.y, a4.z, a4.w};
            float ev[4] = {e4.x, e4.y, e4.z, e4.w};
#pragma unroll
            for (int u = 0; u < 4; u++) {
                if (av[u] != 0.f) {
                    int d = dOff + u;
                    int slot = atomicAdd(&cnt[d], 1);
                    if (slot < CAP) { csh[d][slot] = gsrc; esh[d][slot] = ev[u] * av[u]; }
                }
            }
        }
        __syncthreads();

        if (tid < TD) deg[b * NN + dst0 + tid] = min(cnt[tid], CAP);
        for (int idx = tid; idx < TD * CAP; idx += 256) {
            int d = idx / CAP, i = idx % CAP;
            if (i < min(cnt[d], CAP)) {
                size_t row = (size_t)(b * NN + dst0 + d);
                cols [row * CAP + i] = (unsigned short)csh[d][i];
                evals[row * CAP + i] = esh[d][i];
            }
        }
    } else if (bid < 256 + 1408) {
        int c = bid - 256;
        if (tid < DD) {
            const float *Wq, *Wk, *Wv, *Ws; __hip_bfloat16* Wt; int n, HD;
            if (c < 512) { Wq = Wq1; Wk = Wk1; Wv = Wv1; Ws = Ws1; Wt = Wt1; n = c;       HD = DD;     }
            else         { Wq = Wq2; Wk = Wk2; Wv = Wv2; Ws = Ws2; Wt = Wt2; n = c - 512; HD = 2 * DD; }
            const float* src; int ld; int col;
            if      (n < HD)     { src = Wq; col = n;          ld = HD; }
            else if (n < 2*HD)   { src = Wk; col = n - HD;     ld = HD; }
            else if (n < 3*HD)   { src = Wv; col = n - 2*HD;   ld = HD; }
            else                 { src = Ws; col = n - 3*HD;   ld = DD; }
            Wt[(size_t)n * DD + tid] = __float2bfloat16(src[(size_t)tid * ld + col]);
        }
    } else {
        // ---- layer-0 projection: 16 rows x 512 cols per block ----
        int row0 = (bid - (256 + 1408)) * 16;
        if (tid < 16) xnode[tid] = node[row0 + tid];
        __syncthreads();
        for (int i = tid; i < TD * 512; i += 256) {
            int r = i >> 9, col = i & 511;
            float xv = xnode[r];
            if (col < DD) {
                q[(size_t)(row0 + r) * QSTR + col] = xv * Wq0[col];
            } else if (col < 2*DD) {
                int lc = col - DD;
                kA[(size_t)(row0 + r) * 256 + lc] = __float2bfloat16(xv * Wk0[lc]);
            } else if (col < 3*DD) {
                int lc = col - 2*DD;
                vA[(size_t)(row0 + r) * 256 + lc] = __float2bfloat16(xv * Wv0[lc]);
            } else {
                int lc = col - 3*DD;
                s[(size_t)(row0 + r) * SSTR + lc] = xv * Ws0[lc];
            }
        }
    }
}

// ---------------------------------------------------------------------------
// Fused sparse attention + next-layer projection (unchanged from round 5).
// k/v bf16. Inner loop unrolled x2 (8 edges/iter): all gathers for both
// 4-edge groups issue before either compute phase (memory-level parallelism).
//   NCOLS == 0 -> final layer, write fp32 to out.
// ---------------------------------------------------------------------------
template<int H, bool MEANH, bool LNRELU, int NCOLS, int HDN, int KVSI, int KVSO>
__global__ __launch_bounds__(1024) void fused_attn(
    float* qio,                                   // in/out, stride QSTR
    const __hip_bfloat16* __restrict__ k,         // stride KVSI
    const __hip_bfloat16* __restrict__ v,         // stride KVSI
    float* sio,                                   // in/out, stride SSTR
    const int* __restrict__ deg,
    const unsigned short* __restrict__ cols,
    const float* __restrict__ evals, const float* __restrict__ We,
    const __hip_bfloat16* __restrict__ Wt,
    __hip_bfloat16* __restrict__ kn, __hip_bfloat16* __restrict__ vn, // stride KVSO
    float* __restrict__ out)
{
    const int HD = H * DD;
    int wid  = threadIdx.x >> 6;       // 0..15
    int lane = threadIdx.x & 63;
    int row0 = blockIdx.x * 16;
    int row  = row0 + wid;
    int sub  = lane >> 4;
    int s    = lane & 15;
    int c0   = lane * 2;

    __shared__ int            jc_s[16][CAP];
    __shared__ float          ev_s[16][CAP];
    __shared__ __hip_bfloat16 xs[16][136];   // +8 bf16 pad (16B-aligned rows)
    int*   jc = jc_s[wid];
    float* ev = ev_s[wid];

    int dg = min(deg[row], CAP);
    for (int m = lane; m < dg; m += 64) {
        jc[m] = (int)cols[(size_t)row * CAP + m];
        ev[m] = evals[(size_t)row * CAP + m];
    }
    // wave-private LDS: no barrier needed (compiler inserts lgkmcnt waits)

    float qh[H][8];
    float qeI[H];
#pragma unroll
    for (int h = 0; h < H; h++) {
        const float* qp = &qio[(size_t)row * QSTR + h * DD + s * 8];
        const float* wp = &We[h * DD + s * 8];
        float pe = 0.f;
#pragma unroll
        for (int t = 0; t < 8; t++) { qh[h][t] = qp[t]; pe += qp[t] * wp[t]; }
#pragma unroll
        for (int off = 1; off < 16; off <<= 1) pe += __shfl_xor(pe, off);
        qeI[h] = pe * INV_SQRT_D;
    }

    float l_acc[H], ew_acc[H], acc[H][2];
#pragma unroll
    for (int h = 0; h < H; h++) { l_acc[h] = 0.f; ew_acc[h] = 0.f; acc[h][0] = 0.f; acc[h][1] = 0.f; }

    for (int m0 = 0; m0 < dg; m0 += 8) {
        int   e0  = m0 + sub,       e1  = m0 + 4 + sub;
        bool  ok0 = e0 < dg,        ok1 = e1 < dg;
        int   ec0 = ok0 ? e0 : m0,  ec1 = ok1 ? e1 : m0;
        int   j0  = jc[ec0],        j1  = jc[ec1];
        float ee0 = ev[ec0],        ee1 = ev[ec1];

        int jb[8];
#pragma unroll
        for (int es = 0; es < 8; es++) jb[es] = jc[(m0 + es < dg) ? m0 + es : m0];

        // issue ALL gathers for both groups up front (memory-level parallelism)
        unsigned int vraw[H][8];
#pragma unroll
        for (int h = 0; h < H; h++)
#pragma unroll
            for (int es = 0; es < 8; es++)
                vraw[h][es] = *(const unsigned int*)&v[(size_t)jb[es] * KVSI + h * DD + c0];
        short8 kk0[H], kk1[H];
#pragma unroll
        for (int h = 0; h < H; h++) {
            kk0[h] = *(const short8*)&k[(size_t)j0 * KVSI + h * DD + s * 8];
            kk1[h] = *(const short8*)&k[(size_t)j1 * KVSI + h * DD + s * 8];
        }

#pragma unroll
        for (int h = 0; h < H; h++) {
            float p0 = qh[h][0]*b2f((unsigned short)kk0[h][0]) + qh[h][1]*b2f((unsigned short)kk0[h][1])
                     + qh[h][2]*b2f((unsigned short)kk0[h][2]) + qh[h][3]*b2f((unsigned short)kk0[h][3])
                     + qh[h][4]*b2f((unsigned short)kk0[h][4]) + qh[h][5]*b2f((unsigned short)kk0[h][5])
                     + qh[h][6]*b2f((unsigned short)kk0[h][6]) + qh[h][7]*b2f((unsigned short)kk0[h][7]);
            float p1 = qh[h][0]*b2f((unsigned short)kk1[h][0]) + qh[h][1]*b2f((unsigned short)kk1[h][1])
                     + qh[h][2]*b2f((unsigned short)kk1[h][2]) + qh[h][3]*b2f((unsigned short)kk1[h][3])
                     + qh[h][4]*b2f((unsigned short)kk1[h][4]) + qh[h][5]*b2f((unsigned short)kk1[h][5])
                     + qh[h][6]*b2f((unsigned short)kk1[h][6]) + qh[h][7]*b2f((unsigned short)kk1[h][7]);
#pragma unroll
            for (int off = 1; off < 16; off <<= 1) {
                p0 += __shfl_xor(p0, off);
                p1 += __shfl_xor(p1, off);
            }
            float sc0 = ok0 ? (p0 * INV_SQRT_D + qeI[h] * ee0) : -1e30f;
            float sc1 = ok1 ? (p1 * INV_SQRT_D + qeI[h] * ee1) : -1e30f;
            float a0 = __expf(fminf(sc0, 60.f));
            float a1 = __expf(fminf(sc1, 60.f));
            l_acc[h]  += a0 + a1;
            ew_acc[h] += a0 * ee0 + a1 * ee1;
            float al0[4], al1[4];
#pragma unroll
            for (int es = 0; es < 4; es++) { al0[es] = __shfl(a0, es * 16); al1[es] = __shfl(a1, es * 16); }
#pragma unroll
            for (int es = 0; es < 4; es++) {
                acc[h][0] += al0[es] * b2f_lo(vraw[h][es]) + al1[es] * b2f_lo(vraw[h][es + 4]);
                acc[h][1] += al0[es] * b2f_hi(vraw[h][es]) + al1[es] * b2f_hi(vraw[h][es + 4]);
            }
        }
    }

    // reduce l/ew across the 4 subgroups (values replicated within subgroup)
    float rh[H][2];
#pragma unroll
    for (int h = 0; h < H; h++) {
        float l  = l_acc[h]  + __shfl_xor(l_acc[h], 16);
        float ew = ew_acc[h] + __shfl_xor(ew_acc[h], 16);
        l  += __shfl_xor(l, 32);
        ew += __shfl_xor(ew, 32);
        float invZ = (l > 0.f) ? 1.f / l : 0.f;
        rh[h][0] = (acc[h][0] + ew * We[h * DD + c0])     * invZ;
        rh[h][1] = (acc[h][1] + ew * We[h * DD + c0 + 1]) * invZ;
    }
    float r0, r1;
    if constexpr (MEANH) {
        r0 = 0.5f * (rh[0][0] + rh[H - 1][0]);
        r1 = 0.5f * (rh[0][1] + rh[H - 1][1]);
    } else {
        r0 = rh[0][0]; r1 = rh[0][1];
    }
    float2 sk = *(const float2*)&sio[(size_t)row * SSTR + c0];
    r0 += sk.x; r1 += sk.y;

    if constexpr (LNRELU) {
        float sum = r0 + r1, sq = r0 * r0 + r1 * r1;
#pragma unroll
        for (int off = 32; off; off >>= 1) { sum += __shfl_xor(sum, off); sq += __shfl_xor(sq, off); }
        float mu  = sum * (1.f / DD);
        float var = sq * (1.f / DD) - mu * mu;
        float rs  = rsqrtf(var + 1e-5f);
        r0 = fmaxf((r0 - mu) * rs, 0.f);
        r1 = fmaxf((r1 - mu) * rs, 0.f);
    }

    if constexpr (NCOLS == 0) {
        float2 res; res.x = r0; res.y = r1;
        *(float2*)&out[(size_t)row * DD + c0] = res;
    } else {
        // stage bf16 x-tile in LDS, then MFMA-project into next-layer buffers
        __hip_bfloat162 o;
        o.x = __float2bfloat16(r0);
        o.y = __float2bfloat16(r1);
        *(__hip_bfloat162*)&xs[wid][c0] = o;
        __syncthreads();   // all attn reads (q/skip/k/v) drained before writes

        int m16 = lane & 15, quad = lane >> 4;
        short8 a[4];
#pragma unroll
        for (int ks = 0; ks < 4; ks++)
            a[ks] = *(const short8*)&xs[m16][ks * 32 + quad * 8];

#pragma unroll 1
        for (int tile = wid; tile < NCOLS / 16; tile += 16) {
            int n0 = tile * 16;
            f32x4 pacc = {0.f, 0.f, 0.f, 0.f};
#pragma unroll
            for (int ks = 0; ks < 4; ks++) {
                const short8* bp = (const short8*)&Wt[(size_t)(n0 + m16) * DD + ks * 32 + quad * 8];
                pacc = __builtin_amdgcn_mfma_f32_16x16x32_bf16(a[ks], *bp, pacc, 0, 0, 0);
            }
            if (n0 < HDN) {                                   // q: fp32 in place
#pragma unroll
                for (int r = 0; r < 4; r++)
                    qio[(size_t)(row0 + quad * 4 + r) * QSTR + n0 + m16] = pacc[r];
            } else if (n0 < 2*HDN) {                          // k: bf16
                int lc = n0 - HDN;
#pragma unroll
                for (int r = 0; r < 4; r++)
                    kn[(size_t)(row0 + quad * 4 + r) * KVSO + lc + m16] = __float2bfloat16(pacc[r]);
            } else if (n0 < 3*HDN) {                          // v: bf16
                int lc = n0 - 2*HDN;
#pragma unroll
                for (int r = 0; r < 4; r++)
                    vn[(size_t)(row0 + quad * 4 + r) * KVSO + lc + m16] = __float2bfloat16(pacc[r]);
            } else {                                          // skip: fp32 in place
                int lc = n0 - 3*HDN;
#pragma unroll
                for (int r = 0; r < 4; r++)
                    sio[(size_t)(row0 + quad * 4 + r) * SSTR + lc + m16] = pacc[r];
            }
        }
    }
}

// ---------------------------------------------------------------------------
extern "C" void kernel_launch(void* const* d_in, const int* in_sizes, int n_in,
                              void* d_out, int out_size, void* d_ws, size_t ws_size,
                              hipStream_t stream)
{
    const float* node = (const float*)d_in[0];
    const float* edge = (const float*)d_in[1];
    const float* A    = (const float*)d_in[2];
    const float* Wq[3] = {(const float*)d_in[3],  (const float*)d_in[8],  (const float*)d_in[13]};
    const float* Wk[3] = {(const float*)d_in[4],  (const float*)d_in[9],  (const float*)d_in[14]};
    const float* Wv[3] = {(const float*)d_in[5],  (const float*)d_in[10], (const float*)d_in[15]};
    const float* We[3] = {(const float*)d_in[6],  (const float*)d_in[11], (const float*)d_in[16]};
    const float* Ws[3] = {(const float*)d_in[7],  (const float*)d_in[12], (const float*)d_in[17]};

    // workspace carve (~15.4 MiB)
    char* p = (char*)d_ws;
    float*          q  = (float*)p;          p += (size_t)BN * QSTR * 4;
    float*          s  = (float*)p;          p += (size_t)BN * SSTR * 4;
    __hip_bfloat16* kA = (__hip_bfloat16*)p; p += (size_t)BN * 256 * 2;
    __hip_bfloat16* vA = (__hip_bfloat16*)p; p += (size_t)BN * 256 * 2;
    __hip_bfloat16* kB = (__hip_bfloat16*)p; p += (size_t)BN * 128 * 2;
    __hip_bfloat16* vB = (__hip_bfloat16*)p; p += (size_t)BN * 128 * 2;
    __hip_bfloat16* Wt1 = (__hip_bfloat16*)p; p += (size_t)512 * DD * 2;
    __hip_bfloat16* Wt2 = (__hip_bfloat16*)p; p += (size_t)896 * DD * 2;
    int*            degb = (int*)p;            p += (size_t)BN * 4;
    float*          evb  = (float*)p;          p += (size_t)BN * CAP * 4;
    unsigned short* colb = (unsigned short*)p; p += (size_t)BN * CAP * 2;

    prep<<<256 + 1408 + BN / 16, 256, 0, stream>>>(
        A, edge, node,
        Wq[0], Wk[0], Wv[0], Ws[0],
        Wq[1], Wk[1], Wv[1], Ws[1],
        Wq[2], Wk[2], Wv[2], Ws[2],
        Wt1, Wt2, q, kA, vA, s, degb, colb, evb);

    // app sequence l = {0,1,2,1,2,1,2}; each kernel = attn(l) + proj(next l)
    fused_attn<1, false, true, 512, 128, 256, 128><<<BN / 16, 1024, 0, stream>>>(   // l0 -> proj l1
        q, kA, vA, s, degb, colb, evb, We[0], Wt1, kB, vB, nullptr);
    fused_attn<1, false, true, 896, 256, 128, 256><<<BN / 16, 1024, 0, stream>>>(   // l1 -> proj l2
        q, kB, vB, s, degb, colb, evb, We[1], Wt2, kA, vA, nullptr);
    fused_attn<2, true, false, 512, 128, 256, 128><<<BN / 16, 1024, 0, stream>>>(   // l2 -> proj l1
        q, kA, vA, s, degb, colb, evb, We[2], Wt1, kB, vB, nullptr);
    fused_attn<1, false, true, 896, 256, 128, 256><<<BN / 16, 1024, 0, stream>>>(   // l1 -> proj l2
        q, kB, vB, s, degb, colb, evb, We[1], Wt2, kA, vA, nullptr);
    fused_attn<2, true, false, 512, 128, 256, 128><<<BN / 16, 1024, 0, stream>>>(   // l2 -> proj l1
        q, kA, vA, s, degb, colb, evb, We[2], Wt1, kB, vB, nullptr);
    fused_attn<1, false, true, 896, 256, 128, 256><<<BN / 16, 1024, 0, stream>>>(   // l1 -> proj l2
        q, kB, vB, s, degb, colb, evb, We[1], Wt2, kA, vA, nullptr);
    fused_attn<2, true, false, 0, 0, 256, 0><<<BN / 16, 1024, 0, stream>>>(         // l2 -> output
        q, kA, vA, s, degb, colb, evb, We[2], nullptr, nullptr, nullptr, (float*)d_out);
}